// Round 7
// baseline (2699.385 us; speedup 1.0000x reference)
//
#include <hip/hip_runtime.h>
#include <math.h>

#define VV (128*128*128)         // 2,097,152 voxels per volume

#define K_GAMMA 1e-3f
#define K_ALPHA 1e-2f
#define K_DTN3  5.9604644775390625e-08f   // (1/8) / 128^3  == 2^-24
#define K_W0    0.04908738521234052f      // 2*pi/128

// ---------------- radix-2 butterflies (DIF fwd / DIT inv), N=128 ------------
// fwd: natural -> bit-reversed, W^-theta. inv: bit-reversed -> natural, W^+theta.
__device__ __forceinline__ void bf_fwd(float* re, float* im, const int stride,
                                       const int lane, const int lh,
                                       const float* __restrict__ twr,
                                       const float* __restrict__ twi) {
  const int h  = 1 << lh;
  const int j  = lane & (h - 1);
  const int i0 = ((lane - j) << 1) + j;
  const int i1 = i0 + h;
  const int tw = j << (6 - lh);
  const float wr = twr[tw], ws = twi[tw];
  const int a = i0 * stride, b = i1 * stride;
  const float ar = re[a], ai = im[a];
  const float br = re[b], bi = im[b];
  re[a] = ar + br;  im[a] = ai + bi;
  const float dr = ar - br, di = ai - bi;
  re[b] = dr * wr + di * ws;   // (dr + i di) * (wr - i ws)
  im[b] = di * wr - dr * ws;
}

__device__ __forceinline__ void bf_inv(float* re, float* im, const int stride,
                                       const int lane, const int lh,
                                       const float* __restrict__ twr,
                                       const float* __restrict__ twi) {
  const int h  = 1 << lh;
  const int j  = lane & (h - 1);
  const int i0 = ((lane - j) << 1) + j;
  const int i1 = i0 + h;
  const int tw = j << (6 - lh);
  const float wr = twr[tw], ws = twi[tw];
  const int a = i0 * stride, b = i1 * stride;
  const float ar = re[a], ai = im[a];
  const float br = re[b], bi = im[b];
  const float cr = br * wr - bi * ws;  // (br + i bi) * (wr + i ws)
  const float ci = br * ws + bi * wr;
  re[a] = ar + cr;  im[a] = ai + ci;
  re[b] = ar - cr;  im[b] = ai - ci;
}

// ---------------- K1: m = L v = gamma*v + alpha*(6v - sum of 6 nbrs) --------
__global__ __launch_bounds__(256) void k_stencil_L(const float* __restrict__ v,
                                                   float* __restrict__ m) {
  const int idx = blockIdx.x * 256 + threadIdx.x;   // over 6*VV
  const int vox = idx & (VV - 1);
  const int r   = idx >> 21;
  const int z = vox & 127, y = (vox >> 7) & 127, x = vox >> 14;
  const float* base = v + (size_t)r * VV;
  const float c = base[vox];
  const int xm = (x - 1) & 127, xp = (x + 1) & 127;
  const int ym = (y - 1) & 127, yp = (y + 1) & 127;
  const int zm = (z - 1) & 127, zp = (z + 1) & 127;
  const float nsum = base[(xm << 14) | (y << 7) | z] + base[(xp << 14) | (y << 7) | z]
                   + base[(x << 14) | (ym << 7) | z] + base[(x << 14) | (yp << 7) | z]
                   + base[(x << 14) | (y << 7) | zm] + base[(x << 14) | (y << 7) | zp];
  m[idx] = K_GAMMA * c + K_ALPHA * (6.0f * c - nsum);
}

// ---------------- fused z+y FFT over a contiguous x-plane -------------------
// One block per (vol p, x). LDS holds the full 128x128 complex plane as SoA
// re/im [y][z] with +1 row padding (conflict-free for both z-lines (stride 1)
// and y-lines (stride 129)). fwd: pack 2 real vols -> complex, FFT z then y.
// inv: in-place on cbuf, FFT y then z (axes commute; DIT consumes the DIF's
// bit-reversed storage directly).
template <bool INV>
__global__ __launch_bounds__(1024) void k_fft_zy(const float* __restrict__ m,
                                                 float2* __restrict__ cbuf) {
  __shared__ float twr[64], twi[64];
  __shared__ float re[128 * 129], im[128 * 129];
  const int tid = threadIdx.x, lane = tid & 63, wv = tid >> 6;   // 16 waves
  if (tid < 64) {
    float s, c; sincosf((float)tid * K_W0, &s, &c);
    twr[tid] = c; twi[tid] = s;
  }
  const int p = blockIdx.x >> 7, x = blockIdx.x & 127;
  float2* cb = cbuf + (size_t)p * VV + (size_t)x * 16384;
  if (!INV) {
    const float* r0 = m + (size_t)(2 * p) * VV + (size_t)x * 16384;
    const float* r1 = r0 + VV;
#pragma unroll
    for (int i = 0; i < 16; ++i) {
      const int e = tid + i * 1024, y = e >> 7, z = e & 127;
      re[y * 129 + z] = r0[e];  im[y * 129 + z] = r1[e];
    }
  } else {
#pragma unroll
    for (int i = 0; i < 16; ++i) {
      const int e = tid + i * 1024, y = e >> 7, z = e & 127;
      const float2 v = cb[e];
      re[y * 129 + z] = v.x;  im[y * 129 + z] = v.y;
    }
  }
  if (!INV) {
    // z-axis (lines fixed y, stride 1), 8 lines per wave
    for (int lh = 6; lh >= 0; --lh) {
      __syncthreads();
#pragma unroll
      for (int l = 0; l < 8; ++l) {
        const int y = (wv << 3) | l;
        bf_fwd(re + y * 129, im + y * 129, 1, lane, lh, twr, twi);
      }
    }
    // y-axis (lines fixed z, stride 129)
    for (int lh = 6; lh >= 0; --lh) {
      __syncthreads();
#pragma unroll
      for (int l = 0; l < 8; ++l) {
        const int z = (wv << 3) | l;
        bf_fwd(re + z, im + z, 129, lane, lh, twr, twi);
      }
    }
  } else {
    // y-axis inverse
    for (int lh = 0; lh <= 6; ++lh) {
      __syncthreads();
#pragma unroll
      for (int l = 0; l < 8; ++l) {
        const int z = (wv << 3) | l;
        bf_inv(re + z, im + z, 129, lane, lh, twr, twi);
      }
    }
    // z-axis inverse
    for (int lh = 0; lh <= 6; ++lh) {
      __syncthreads();
#pragma unroll
      for (int l = 0; l < 8; ++l) {
        const int y = (wv << 3) | l;
        bf_inv(re + y * 129, im + y * 129, 1, lane, lh, twr, twi);
      }
    }
  }
  __syncthreads();
#pragma unroll
  for (int i = 0; i < 16; ++i) {
    const int e = tid + i * 1024, y = e >> 7, z = e & 127;
    cb[e] = make_float2(re[y * 129 + z], im[y * 129 + z]);
  }
}

// ---------------- fused fwd-x FFT + spectral scale + inv-x FFT --------------
// z-tile of 16 (128B rows -> full-cache-line global access). LDS re/im
// [x][zz] padded stride 17 (17 coprime 32 -> conflict-free x-lines).
// tt[p] = 2-2cos(2*pi*bitrev7(p)/128): correct at bit-reversed storage for
// all three axes (x mid-kernel, y/z already DIF-transformed).
__global__ __launch_bounds__(512) void k_fft_x_fused(float2* __restrict__ cbuf) {
  __shared__ float twr[64], twi[64], tt[128];
  __shared__ float re[128 * 17], im[128 * 17];
  const int tid = threadIdx.x, lane = tid & 63, wv = tid >> 6;   // 8 waves
  if (tid < 64) {
    float s, c; sincosf((float)tid * K_W0, &s, &c);
    twr[tid] = c; twi[tid] = s;
  }
  if (tid < 128) {
    const int br = (int)(__brev((unsigned)tid) >> 25);
    tt[tid] = 2.0f - 2.0f * cosf((float)br * K_W0);
  }
  const int bid = blockIdx.x;                 // 3 * 128 * 8
  const int p = bid >> 10, rem = bid & 1023;
  const int y = rem >> 3, z0 = (rem & 7) << 4;
  float2* base = cbuf + (size_t)p * VV + (size_t)(y * 128 + z0);
#pragma unroll
  for (int i = 0; i < 4; ++i) {
    const int e = tid + i * 512, xx = e >> 4, zz = e & 15;
    const float2 v = base[(size_t)xx * 16384 + zz];
    re[xx * 17 + zz] = v.x;  im[xx * 17 + zz] = v.y;
  }
  // fwd x: 16 lines (zz), wave wv owns zz=wv and zz=wv+8
  for (int lh = 6; lh >= 0; --lh) {
    __syncthreads();
#pragma unroll
    for (int l = 0; l < 2; ++l) {
      const int zz = wv + (l << 3);
      bf_fwd(re + zz, im + zz, 17, lane, lh, twr, twi);
    }
  }
  __syncthreads();
  // spectral scale on own lines
  {
    const float tyv = tt[y];
#pragma unroll
    for (int l = 0; l < 2; ++l) {
      const int zz = wv + (l << 3);
      const float tzv = tt[z0 + zz];
#pragma unroll
      for (int i = lane; i < 128; i += 64) {
        const float sc = K_DTN3 / (K_GAMMA + K_ALPHA * (tt[i] + tyv + tzv));
        re[i * 17 + zz] *= sc;
        im[i * 17 + zz] *= sc;
      }
    }
  }
  // inv x
  for (int lh = 0; lh <= 6; ++lh) {
    __syncthreads();
#pragma unroll
    for (int l = 0; l < 2; ++l) {
      const int zz = wv + (l << 3);
      bf_inv(re + zz, im + zz, 17, lane, lh, twr, twi);
    }
  }
  __syncthreads();
#pragma unroll
  for (int i = 0; i < 4; ++i) {
    const int e = tid + i * 512, xx = e >> 4, zz = e & 15;
    base[(size_t)xx * 16384 + zz] = make_float2(re[xx * 17 + zz], im[xx * 17 + zz]);
  }
}

// ---------------- pullback: 2 voxels (z even, z+1) per thread ----------------
struct Corner { int o[8]; float w[8]; };

__device__ __forceinline__ Corner mk_corner(float cx, float cy, float cz) {
  Corner c;
  const float flx = floorf(cx), fly = floorf(cy), flz = floorf(cz);
  const float wx = cx - flx, wy = cy - fly, wz = cz - flz;
  const int x0 = ((int)flx) & 127, y0 = ((int)fly) & 127, z0 = ((int)flz) & 127;
  const int x1 = (x0 + 1) & 127,  y1 = (y0 + 1) & 127,  z1 = (z0 + 1) & 127;
  c.o[0] = (x0 * 128 + y0) * 128 + z0;  c.o[1] = (x0 * 128 + y0) * 128 + z1;
  c.o[2] = (x0 * 128 + y1) * 128 + z0;  c.o[3] = (x0 * 128 + y1) * 128 + z1;
  c.o[4] = (x1 * 128 + y0) * 128 + z0;  c.o[5] = (x1 * 128 + y0) * 128 + z1;
  c.o[6] = (x1 * 128 + y1) * 128 + z0;  c.o[7] = (x1 * 128 + y1) * 128 + z1;
  const float ux = 1.f - wx, uy = 1.f - wy, uz = 1.f - wz;
  c.w[0] = ux * uy * uz;  c.w[1] = ux * uy * wz;
  c.w[2] = ux * wy * uz;  c.w[3] = ux * wy * wz;
  c.w[4] = wx * uy * uz;  c.w[5] = wx * uy * wz;
  c.w[6] = wx * wy * uz;  c.w[7] = wx * wy * wz;
  return c;
}

__device__ __forceinline__ float tri8(const float* __restrict__ V, const Corner& c) {
  float s = 0.f;
#pragma unroll
  for (int k = 0; k < 8; ++k) s += c.w[k] * V[c.o[k]];
  return s;
}

__global__ __launch_bounds__(256) void k_pullback(const float4* __restrict__ sv4,
                                                  const float* __restrict__ phiA,
                                                  const float* __restrict__ mA,
                                                  float* __restrict__ phiB,
                                                  float* __restrict__ mB) {
  const int idx = blockIdx.x * 256 + threadIdx.x;   // VV threads (pair each)
  const int b   = idx >> 20;                        // VV/2 pairs per batch
  const int pr  = idx & ((VV >> 1) - 1);
  const int vox = pr << 1;                          // even voxel; pair never wraps z
  const int z = vox & 127, y = (vox >> 7) & 127, x = vox >> 14;
  // sv channel r=b*3+c lives at complex vol r>>1, component r&1; float4 at
  // pair pr of vol q = (c0@zA, c1@zA, c0@zB, c1@zB).
  float d0A, d1A, d2A, d0B, d1B, d2B;
  if (b == 0) {
    const float4 f0 = sv4[pr];                    // vol0: ch0, ch1
    const float4 f1 = sv4[(VV >> 1) + pr];        // vol1: ch2 (c0)
    d0A = f0.x; d1A = f0.y; d0B = f0.z; d1B = f0.w;
    d2A = f1.x; d2B = f1.z;
  } else {
    const float4 f1 = sv4[(VV >> 1) + pr];        // vol1: ch3 (c1)
    const float4 f2 = sv4[2 * (VV >> 1) + pr];    // vol2: ch4, ch5
    d0A = f1.y; d0B = f1.w;
    d1A = f2.x; d2A = f2.y; d1B = f2.z; d2B = f2.w;
  }
  const Corner cA = mk_corner((float)x + d0A, (float)y + d1A, (float)z + d2A);
  const Corner cB = mk_corner((float)x + d0B, (float)y + d1B, (float)(z + 1) + d2B);
  const float ddA[3] = {d0A, d1A, d2A};
  const float ddB[3] = {d0B, d1B, d2B};
  const size_t sb = (size_t)b * 3 * VV;
#pragma unroll
  for (int c = 0; c < 3; ++c) {
    const size_t vb = sb + (size_t)c * VV;
    const float* P = phiA + vb;
    const float gpA = tri8(P, cA), gpB = tri8(P, cB);
    *(float2*)(phiB + vb + vox) = make_float2(gpA + ddA[c], gpB + ddB[c]);
    const float* M = mA + vb;
    const float gmA = tri8(M, cA), gmB = tri8(M, cB);
    *(float2*)(mB + vb + vox) = make_float2(gmA, gmB);
  }
}

// ---------------- host ------------------------------------------------------
// ws layout (floats): [phi1: 6*VV][mA: 6*VV][mB: 6*VV][cbuf: 3*VV complex]
// total 4 * 6*VV * 4B = 192 MiB.
extern "C" void kernel_launch(void* const* d_in, const int* in_sizes, int n_in,
                              void* d_out, int out_size, void* d_ws, size_t ws_size,
                              hipStream_t stream) {
  (void)in_sizes; (void)n_in; (void)out_size; (void)ws_size;
  const float* v = (const float*)d_in[0];
  float* phi0 = (float*)d_out;                       // phi buffer A (result here)
  float* ws   = (float*)d_ws;
  const size_t FV = (size_t)6 * VV;                  // floats per full field
  float* phi1 = ws;                                  // phi buffer B
  float* mA   = ws + FV;
  float* mB   = ws + 2 * FV;
  float2* cbuf = (float2*)(ws + 3 * FV);             // 3 complex vols (= sv packed)

  hipMemsetAsync(phi0, 0, FV * sizeof(float), stream);
  k_stencil_L<<<dim3((unsigned)(FV / 256)), dim3(256), 0, stream>>>(v, mA);

  float* phiA = phi0; float* phiB = phi1;
  float* ma = mA;     float* mb = mB;
  for (int s = 0; s < 8; ++s) {
    k_fft_zy<false><<<dim3(384), dim3(1024), 0, stream>>>(ma, cbuf);
    k_fft_x_fused<<<dim3(3072), dim3(512), 0, stream>>>(cbuf);
    k_fft_zy<true><<<dim3(384), dim3(1024), 0, stream>>>(ma, cbuf);
    k_pullback<<<dim3(VV / 256), dim3(256), 0, stream>>>((const float4*)cbuf,
                                                         phiA, ma, phiB, mb);
    float* t = phiA; phiA = phiB; phiB = t;
    t = ma; ma = mb; mb = t;
  }
  // 8 swaps (even): final phi ends in d_out
}

// Round 9
// 2418.389 us; speedup vs baseline: 1.1162x; 1.1162x over previous
//
#include <hip/hip_runtime.h>
#include <math.h>

#define VV (128*128*128)         // 2,097,152 voxels per volume

#define K_GAMMA 1e-3f
#define K_ALPHA 1e-2f
#define K_DTN3  5.9604644775390625e-08f   // (1/8) / 128^3  == 2^-24
#define K_W0    0.04908738521234052f      // 2*pi/128

// ============ shuffle-register FFT, N=128, one line per 64-lane wave ========
// Mapping: lane l holds positions l (lo) and l+64 (hi) — fixed through all
// stages, so storage order matches the (verified) LDS in-place DIF/DIT:
// fwd DIF natural->bit-reversed (W^-), inv DIT bit-reversed->natural (W^+).
// Stage h=64 is in-lane; stages h<=32 exchange via __shfl_xor(h).
__device__ __forceinline__ void sh_fwd(float& rlo, float& ilo, float& rhi, float& ihi,
                                       const int lane,
                                       const float* __restrict__ twr,
                                       const float* __restrict__ twi) {
  {   // lh=6, h=64: pair (l, l+64) in-lane, tw idx = l
    const float wr = twr[lane], ws = twi[lane];
    const float dr = rlo - rhi, di = ilo - ihi;
    rlo += rhi;  ilo += ihi;
    rhi = dr * wr + di * ws;    // (dr + i di)*(wr - i ws)
    ihi = di * wr - dr * ws;
  }
#pragma unroll
  for (int lh = 5; lh >= 0; --lh) {
    const int h  = 1 << lh;
    const int up = lane & h;
    const int ti = (lane & (h - 1)) << (6 - lh);
    const float wr = twr[ti], ws = twi[ti];
    float pr = __shfl_xor(rlo, h), pi = __shfl_xor(ilo, h);
    float dr = up ? (pr - rlo) : (rlo + pr);
    float di = up ? (pi - ilo) : (ilo + pi);
    rlo = up ? (dr * wr + di * ws) : dr;
    ilo = up ? (di * wr - dr * ws) : di;
    pr = __shfl_xor(rhi, h);  pi = __shfl_xor(ihi, h);
    dr = up ? (pr - rhi) : (rhi + pr);
    di = up ? (pi - ihi) : (ihi + pi);
    rhi = up ? (dr * wr + di * ws) : dr;
    ihi = up ? (di * wr - dr * ws) : di;
  }
}

__device__ __forceinline__ void sh_inv(float& rlo, float& ilo, float& rhi, float& ihi,
                                       const int lane,
                                       const float* __restrict__ twr,
                                       const float* __restrict__ twi) {
#pragma unroll
  for (int lh = 0; lh <= 5; ++lh) {
    const int h  = 1 << lh;
    const int up = lane & h;
    const int ti = (lane & (h - 1)) << (6 - lh);
    const float wr = twr[ti], ws = twi[ti];
    float pr = __shfl_xor(rlo, h), pi = __shfl_xor(ilo, h);
    float ar = up ? pr : rlo,  ai = up ? pi : ilo;
    float br = up ? rlo : pr,  bi = up ? ilo : pi;
    float cr = br * wr - bi * ws, ci = br * ws + bi * wr;   // b * (wr + i ws)
    rlo = up ? (ar - cr) : (ar + cr);
    ilo = up ? (ai - ci) : (ai + ci);
    pr = __shfl_xor(rhi, h);  pi = __shfl_xor(ihi, h);
    ar = up ? pr : rhi;  ai = up ? pi : ihi;
    br = up ? rhi : pr;  bi = up ? ihi : pi;
    cr = br * wr - bi * ws;  ci = br * ws + bi * wr;
    rhi = up ? (ar - cr) : (ar + cr);
    ihi = up ? (ai - ci) : (ai + ci);
  }
  {   // lh=6, h=64 in-lane, tw idx = l
    const float wr = twr[lane], ws = twi[lane];
    const float cr = rhi * wr - ihi * ws, ci = rhi * ws + ihi * wr;
    rhi = rlo - cr;  ihi = ilo - ci;
    rlo += cr;       ilo += ci;
  }
}

// ---------------- K1: m = L v = gamma*v + alpha*(6v - sum of 6 nbrs) --------
__global__ __launch_bounds__(256) void k_stencil_L(const float* __restrict__ v,
                                                   float* __restrict__ m) {
  const int idx = blockIdx.x * 256 + threadIdx.x;   // over 6*VV
  const int vox = idx & (VV - 1);
  const int r   = idx >> 21;
  const int z = vox & 127, y = (vox >> 7) & 127, x = vox >> 14;
  const float* base = v + (size_t)r * VV;
  const float c = base[vox];
  const int xm = (x - 1) & 127, xp = (x + 1) & 127;
  const int ym = (y - 1) & 127, yp = (y + 1) & 127;
  const int zm = (z - 1) & 127, zp = (z + 1) & 127;
  const float nsum = base[(xm << 14) | (y << 7) | z] + base[(xp << 14) | (y << 7) | z]
                   + base[(x << 14) | (ym << 7) | z] + base[(x << 14) | (yp << 7) | z]
                   + base[(x << 14) | (y << 7) | zm] + base[(x << 14) | (y << 7) | zp];
  m[idx] = K_GAMMA * c + K_ALPHA * (6.0f * c - nsum);
}

// ---------------- fused z+y forward FFT over one x-plane --------------------
// regs(z-fft via shfl) -> LDS -> regs(y-fft via shfl) -> LDS -> bulk store.
// LDS rows padded to 129 (stride 129 == 1 mod 32: conflict-free columns).
__global__ __launch_bounds__(1024) void k_fft_zy_f(const float* __restrict__ m,
                                                   float2* __restrict__ cbuf) {
  __shared__ float twr[64], twi[64];
  __shared__ float s_re[128 * 129], s_im[128 * 129];
  const int tid = threadIdx.x, lane = tid & 63, wv = tid >> 6;   // 16 waves
  if (tid < 64) {
    float s, c; sincosf((float)tid * K_W0, &s, &c);
    twr[tid] = c; twi[tid] = s;
  }
  const int p = blockIdx.x >> 7, x = blockIdx.x & 127;
  const float* r0 = m + (size_t)(2 * p) * VV + (size_t)x * 16384;
  const float* r1 = r0 + VV;
  // load this wave's 8 z-lines (rows y = wv*8+l) into registers
  float rlo[8], ilo[8], rhi[8], ihi[8];
#pragma unroll
  for (int l = 0; l < 8; ++l) {
    const int row = ((wv << 3) | l) << 7;
    rlo[l] = r0[row + lane];  rhi[l] = r0[row + lane + 64];
    ilo[l] = r1[row + lane];  ihi[l] = r1[row + lane + 64];
  }
  __syncthreads();                       // twiddles ready
#pragma unroll
  for (int l = 0; l < 8; ++l) {
    sh_fwd(rlo[l], ilo[l], rhi[l], ihi[l], lane, twr, twi);
    const int y = (wv << 3) | l;
    s_re[y * 129 + lane] = rlo[l];  s_re[y * 129 + lane + 64] = rhi[l];
    s_im[y * 129 + lane] = ilo[l];  s_im[y * 129 + lane + 64] = ihi[l];
  }
  __syncthreads();
  // y-FFT: wave handles columns z = wv*8+l
#pragma unroll
  for (int l = 0; l < 8; ++l) {
    const int z = (wv << 3) | l;
    float arl = s_re[lane * 129 + z],        ail = s_im[lane * 129 + z];
    float arh = s_re[(lane + 64) * 129 + z], aih = s_im[(lane + 64) * 129 + z];
    sh_fwd(arl, ail, arh, aih, lane, twr, twi);
    s_re[lane * 129 + z] = arl;  s_re[(lane + 64) * 129 + z] = arh;
    s_im[lane * 129 + z] = ail;  s_im[(lane + 64) * 129 + z] = aih;
  }
  __syncthreads();
  float2* cb = cbuf + (size_t)p * VV + (size_t)x * 16384;
#pragma unroll
  for (int i = 0; i < 16; ++i) {
    const int e = tid + i * 1024, y = e >> 7, z = e & 127;
    cb[e] = make_float2(s_re[y * 129 + z], s_im[y * 129 + z]);
  }
}

// ---------------- fused y+z inverse FFT over one x-plane --------------------
// bulk load -> LDS -> regs(y-inv) -> LDS -> regs(z-inv) -> direct store.
__global__ __launch_bounds__(1024) void k_fft_zy_i(float2* __restrict__ cbuf) {
  __shared__ float twr[64], twi[64];
  __shared__ float s_re[128 * 129], s_im[128 * 129];
  const int tid = threadIdx.x, lane = tid & 63, wv = tid >> 6;
  if (tid < 64) {
    float s, c; sincosf((float)tid * K_W0, &s, &c);
    twr[tid] = c; twi[tid] = s;
  }
  const int p = blockIdx.x >> 7, x = blockIdx.x & 127;
  float2* cb = cbuf + (size_t)p * VV + (size_t)x * 16384;
#pragma unroll
  for (int i = 0; i < 16; ++i) {
    const int e = tid + i * 1024, y = e >> 7, z = e & 127;
    const float2 v = cb[e];
    s_re[y * 129 + z] = v.x;  s_im[y * 129 + z] = v.y;
  }
  __syncthreads();
  // y-inverse on columns z = wv*8+l
#pragma unroll
  for (int l = 0; l < 8; ++l) {
    const int z = (wv << 3) | l;
    float arl = s_re[lane * 129 + z],        ail = s_im[lane * 129 + z];
    float arh = s_re[(lane + 64) * 129 + z], aih = s_im[(lane + 64) * 129 + z];
    sh_inv(arl, ail, arh, aih, lane, twr, twi);
    s_re[lane * 129 + z] = arl;  s_re[(lane + 64) * 129 + z] = arh;
    s_im[lane * 129 + z] = ail;  s_im[(lane + 64) * 129 + z] = aih;
  }
  __syncthreads();
  // z-inverse on rows y = wv*8+l, store directly (coalesced float2 rows)
#pragma unroll
  for (int l = 0; l < 8; ++l) {
    const int y = (wv << 3) | l;
    float arl = s_re[y * 129 + lane],      ail = s_im[y * 129 + lane];
    float arh = s_re[y * 129 + lane + 64], aih = s_im[y * 129 + lane + 64];
    sh_inv(arl, ail, arh, aih, lane, twr, twi);
    cb[(y << 7) + lane]      = make_float2(arl, ail);
    cb[(y << 7) + lane + 64] = make_float2(arh, aih);
  }
}

// ---------------- fused fwd-x FFT + spectral scale + inv-x FFT --------------
// z-tile of 16 for fixed (vol, y). LDS [x][zz] stride 17 (coprime 32 ->
// conflict-free x-columns). FFTs in registers via shfl; scale in registers.
// tt[p] = 2-2cos(2*pi*bitrev7(p)/128): t at bit-reversed storage positions.
__global__ __launch_bounds__(512) void k_fft_x_fused(float2* __restrict__ cbuf) {
  __shared__ float twr[64], twi[64], tt[128];
  __shared__ float s_re[128 * 17], s_im[128 * 17];
  const int tid = threadIdx.x, lane = tid & 63, wv = tid >> 6;   // 8 waves
  if (tid < 64) {
    float s, c; sincosf((float)tid * K_W0, &s, &c);
    twr[tid] = c; twi[tid] = s;
  }
  if (tid < 128) {
    const int br = (int)(__brev((unsigned)tid) >> 25);   // 7-bit bit-reverse
    tt[tid] = 2.0f - 2.0f * cosf((float)br * K_W0);
  }
  const int bid = blockIdx.x;                 // 3 * 128 * 8
  const int p = bid >> 10, rem = bid & 1023;
  const int y = rem >> 3, z0 = (rem & 7) << 4;
  float2* base = cbuf + (size_t)p * VV + (size_t)(y * 128 + z0);
#pragma unroll
  for (int i = 0; i < 4; ++i) {
    const int e = tid + i * 512, xx = e >> 4, zz = e & 15;
    const float2 v = base[(size_t)xx * 16384 + zz];
    s_re[xx * 17 + zz] = v.x;  s_im[xx * 17 + zz] = v.y;
  }
  __syncthreads();
  const float tyv = tt[y];
#pragma unroll
  for (int l = 0; l < 2; ++l) {
    const int zz = wv + (l << 3);
    float arl = s_re[lane * 17 + zz],        ail = s_im[lane * 17 + zz];
    float arh = s_re[(lane + 64) * 17 + zz], aih = s_im[(lane + 64) * 17 + zz];
    sh_fwd(arl, ail, arh, aih, lane, twr, twi);
    const float tzv = tt[z0 + zz];
    const float slo = K_DTN3 / (K_GAMMA + K_ALPHA * (tt[lane] + tyv + tzv));
    const float shi = K_DTN3 / (K_GAMMA + K_ALPHA * (tt[lane + 64] + tyv + tzv));
    arl *= slo;  ail *= slo;  arh *= shi;  aih *= shi;
    sh_inv(arl, ail, arh, aih, lane, twr, twi);
    s_re[lane * 17 + zz] = arl;  s_re[(lane + 64) * 17 + zz] = arh;
    s_im[lane * 17 + zz] = ail;  s_im[(lane + 64) * 17 + zz] = aih;
  }
  __syncthreads();
#pragma unroll
  for (int i = 0; i < 4; ++i) {
    const int e = tid + i * 512, xx = e >> 4, zz = e & 15;
    base[(size_t)xx * 16384 + zz] = make_float2(s_re[xx * 17 + zz], s_im[xx * 17 + zz]);
  }
}

// ---------------- pullback: deep-batched gathers, 1 voxel/thread ------------
// launch_bounds(256, 2): VGPR cap 256 -> compiler can keep all 48 corner
// loads in flight (phase 1) before the lerp reduction (phase 2).
__global__ __launch_bounds__(256, 2) void k_pullback(const float* __restrict__ svc,
                                                     const float* __restrict__ phiA,
                                                     const float* __restrict__ mA,
                                                     float* __restrict__ phiB,
                                                     float* __restrict__ mB) {
  const int idx = blockIdx.x * 256 + threadIdx.x;   // over 2*VV
  const int b   = idx >> 21;
  const int vox = idx & (VV - 1);
  const int z = vox & 127, y = (vox >> 7) & 127, x = vox >> 14;
  // sv channel r=b*3+c lives at complex vol r>>1, component r&1
  const int r0 = b * 3;
  const float d0 = svc[(size_t)((r0)     >> 1) * 2 * VV + ((size_t)vox << 1) + ((r0)     & 1)];
  const float d1 = svc[(size_t)((r0 + 1) >> 1) * 2 * VV + ((size_t)vox << 1) + ((r0 + 1) & 1)];
  const float d2 = svc[(size_t)((r0 + 2) >> 1) * 2 * VV + ((size_t)vox << 1) + ((r0 + 2) & 1)];
  const float cx = (float)x + d0, cy = (float)y + d1, cz = (float)z + d2;
  const float flx = floorf(cx), fly = floorf(cy), flz = floorf(cz);
  const float wx = cx - flx, wy = cy - fly, wz = cz - flz;
  const int x0 = ((int)flx) & 127, y0 = ((int)fly) & 127, z0 = ((int)flz) & 127;
  const int x1 = (x0 + 1) & 127,  y1 = (y0 + 1) & 127,  z1 = (z0 + 1) & 127;
  int o[8];
  o[0] = (x0 * 128 + y0) * 128 + z0;  o[1] = (x0 * 128 + y0) * 128 + z1;
  o[2] = (x0 * 128 + y1) * 128 + z0;  o[3] = (x0 * 128 + y1) * 128 + z1;
  o[4] = (x1 * 128 + y0) * 128 + z0;  o[5] = (x1 * 128 + y0) * 128 + z1;
  o[6] = (x1 * 128 + y1) * 128 + z0;  o[7] = (x1 * 128 + y1) * 128 + z1;
  const size_t sb = (size_t)b * 3 * VV;
  // -------- phase 1: issue ALL 48 gathers --------
  float g[6][8];
#pragma unroll
  for (int c = 0; c < 3; ++c) {
    const float* P = phiA + sb + (size_t)c * VV;
#pragma unroll
    for (int k = 0; k < 8; ++k) g[c][k] = P[o[k]];
  }
#pragma unroll
  for (int c = 0; c < 3; ++c) {
    const float* M = mA + sb + (size_t)c * VV;
#pragma unroll
    for (int k = 0; k < 8; ++k) g[3 + c][k] = M[o[k]];
  }
  // -------- weights (VALU, overlaps load latency) --------
  const float ux = 1.f - wx, uy = 1.f - wy, uz = 1.f - wz;
  float w[8];
  w[0] = ux * uy * uz;  w[1] = ux * uy * wz;
  w[2] = ux * wy * uz;  w[3] = ux * wy * wz;
  w[4] = wx * uy * uz;  w[5] = wx * uy * wz;
  w[6] = wx * wy * uz;  w[7] = wx * wy * wz;
  const float dd[3] = {d0, d1, d2};
  // -------- phase 2: reduce + store --------
#pragma unroll
  for (int c = 0; c < 3; ++c) {
    float sp = 0.f, sm = 0.f;
#pragma unroll
    for (int k = 0; k < 8; ++k) { sp += w[k] * g[c][k];  sm += w[k] * g[3 + c][k]; }
    phiB[sb + (size_t)c * VV + vox] = sp + dd[c];
    mB[sb + (size_t)c * VV + vox]   = sm;
  }
}

// ---------------- host ------------------------------------------------------
// ws layout (floats): [phi1: 6*VV][mA: 6*VV][mB: 6*VV][cbuf: 3*VV complex]
// total 4 * 6*VV * 4B = 192 MiB.
extern "C" void kernel_launch(void* const* d_in, const int* in_sizes, int n_in,
                              void* d_out, int out_size, void* d_ws, size_t ws_size,
                              hipStream_t stream) {
  (void)in_sizes; (void)n_in; (void)out_size; (void)ws_size;
  const float* v = (const float*)d_in[0];
  float* phi0 = (float*)d_out;                       // phi buffer A (result here)
  float* ws   = (float*)d_ws;
  const size_t FV = (size_t)6 * VV;                  // floats per full field
  float* phi1 = ws;                                  // phi buffer B
  float* mA   = ws + FV;
  float* mB   = ws + 2 * FV;
  float2* cbuf = (float2*)(ws + 3 * FV);             // 3 complex vols (= sv packed)

  hipMemsetAsync(phi0, 0, FV * sizeof(float), stream);
  k_stencil_L<<<dim3((unsigned)(FV / 256)), dim3(256), 0, stream>>>(v, mA);

  float* phiA = phi0; float* phiB = phi1;
  float* ma = mA;     float* mb = mB;
  for (int s = 0; s < 8; ++s) {
    k_fft_zy_f<<<dim3(384), dim3(1024), 0, stream>>>(ma, cbuf);
    k_fft_x_fused<<<dim3(3072), dim3(512), 0, stream>>>(cbuf);
    k_fft_zy_i<<<dim3(384), dim3(1024), 0, stream>>>(cbuf);
    k_pullback<<<dim3(16384), dim3(256), 0, stream>>>((const float*)cbuf,
                                                      phiA, ma, phiB, mb);
    float* t = phiA; phiA = phiB; phiB = t;
    t = ma; ma = mb; mb = t;
  }
  // 8 swaps (even): final phi ends in d_out
}

// Round 10
// 2416.456 us; speedup vs baseline: 1.1171x; 1.0008x over previous
//
#include <hip/hip_runtime.h>
#include <math.h>

#define VV (128*128*128)         // 2,097,152 voxels per volume

#define K_GAMMA 1e-3f
#define K_ALPHA 1e-2f
#define K_DTN3  5.9604644775390625e-08f   // (1/8) / 128^3  == 2^-24
#define K_W0    0.04908738521234052f      // 2*pi/128

// ============ shuffle-register FFT, N=128, one line per 64-lane wave ========
// Mapping: lane l holds positions l (lo) and l+64 (hi) — fixed through all
// stages, so storage order matches the (verified) LDS in-place DIF/DIT:
// fwd DIF natural->bit-reversed (W^-), inv DIT bit-reversed->natural (W^+).
// Stage h=64 is in-lane; stages h<=32 exchange via __shfl_xor(h).
__device__ __forceinline__ void sh_fwd(float& rlo, float& ilo, float& rhi, float& ihi,
                                       const int lane,
                                       const float* __restrict__ twr,
                                       const float* __restrict__ twi) {
  {   // lh=6, h=64: pair (l, l+64) in-lane, tw idx = l
    const float wr = twr[lane], ws = twi[lane];
    const float dr = rlo - rhi, di = ilo - ihi;
    rlo += rhi;  ilo += ihi;
    rhi = dr * wr + di * ws;    // (dr + i di)*(wr - i ws)
    ihi = di * wr - dr * ws;
  }
#pragma unroll
  for (int lh = 5; lh >= 0; --lh) {
    const int h  = 1 << lh;
    const int up = lane & h;
    const int ti = (lane & (h - 1)) << (6 - lh);
    const float wr = twr[ti], ws = twi[ti];
    float pr = __shfl_xor(rlo, h), pi = __shfl_xor(ilo, h);
    float dr = up ? (pr - rlo) : (rlo + pr);
    float di = up ? (pi - ilo) : (ilo + pi);
    rlo = up ? (dr * wr + di * ws) : dr;
    ilo = up ? (di * wr - dr * ws) : di;
    pr = __shfl_xor(rhi, h);  pi = __shfl_xor(ihi, h);
    dr = up ? (pr - rhi) : (rhi + pr);
    di = up ? (pi - ihi) : (ihi + pi);
    rhi = up ? (dr * wr + di * ws) : dr;
    ihi = up ? (di * wr - dr * ws) : di;
  }
}

__device__ __forceinline__ void sh_inv(float& rlo, float& ilo, float& rhi, float& ihi,
                                       const int lane,
                                       const float* __restrict__ twr,
                                       const float* __restrict__ twi) {
#pragma unroll
  for (int lh = 0; lh <= 5; ++lh) {
    const int h  = 1 << lh;
    const int up = lane & h;
    const int ti = (lane & (h - 1)) << (6 - lh);
    const float wr = twr[ti], ws = twi[ti];
    float pr = __shfl_xor(rlo, h), pi = __shfl_xor(ilo, h);
    float ar = up ? pr : rlo,  ai = up ? pi : ilo;
    float br = up ? rlo : pr,  bi = up ? ilo : pi;
    float cr = br * wr - bi * ws, ci = br * ws + bi * wr;   // b * (wr + i ws)
    rlo = up ? (ar - cr) : (ar + cr);
    ilo = up ? (ai - ci) : (ai + ci);
    pr = __shfl_xor(rhi, h);  pi = __shfl_xor(ihi, h);
    ar = up ? pr : rhi;  ai = up ? pi : ihi;
    br = up ? rhi : pr;  bi = up ? ihi : pi;
    cr = br * wr - bi * ws;  ci = br * ws + bi * wr;
    rhi = up ? (ar - cr) : (ar + cr);
    ihi = up ? (ai - ci) : (ai + ci);
  }
  {   // lh=6, h=64 in-lane, tw idx = l
    const float wr = twr[lane], ws = twi[lane];
    const float cr = rhi * wr - ihi * ws, ci = rhi * ws + ihi * wr;
    rhi = rlo - cr;  ihi = ilo - ci;
    rlo += cr;       ilo += ci;
  }
}

// ---------------- K1: m = L v = gamma*v + alpha*(6v - sum of 6 nbrs) --------
__global__ __launch_bounds__(256) void k_stencil_L(const float* __restrict__ v,
                                                   float* __restrict__ m) {
  const int idx = blockIdx.x * 256 + threadIdx.x;   // over 6*VV
  const int vox = idx & (VV - 1);
  const int r   = idx >> 21;
  const int z = vox & 127, y = (vox >> 7) & 127, x = vox >> 14;
  const float* base = v + (size_t)r * VV;
  const float c = base[vox];
  const int xm = (x - 1) & 127, xp = (x + 1) & 127;
  const int ym = (y - 1) & 127, yp = (y + 1) & 127;
  const int zm = (z - 1) & 127, zp = (z + 1) & 127;
  const float nsum = base[(xm << 14) | (y << 7) | z] + base[(xp << 14) | (y << 7) | z]
                   + base[(x << 14) | (ym << 7) | z] + base[(x << 14) | (yp << 7) | z]
                   + base[(x << 14) | (y << 7) | zm] + base[(x << 14) | (y << 7) | zp];
  m[idx] = K_GAMMA * c + K_ALPHA * (6.0f * c - nsum);
}

// ---------------- fused z+y forward FFT over one x-plane --------------------
// regs(z-fft via shfl) -> LDS -> regs(y-fft via shfl) -> LDS -> bulk store.
// LDS rows padded to 129 (stride 129 == 1 mod 32: conflict-free columns).
__global__ __launch_bounds__(1024) void k_fft_zy_f(const float* __restrict__ m,
                                                   float2* __restrict__ cbuf) {
  __shared__ float twr[64], twi[64];
  __shared__ float s_re[128 * 129], s_im[128 * 129];
  const int tid = threadIdx.x, lane = tid & 63, wv = tid >> 6;   // 16 waves
  if (tid < 64) {
    float s, c; sincosf((float)tid * K_W0, &s, &c);
    twr[tid] = c; twi[tid] = s;
  }
  const int p = blockIdx.x >> 7, x = blockIdx.x & 127;
  const float* r0 = m + (size_t)(2 * p) * VV + (size_t)x * 16384;
  const float* r1 = r0 + VV;
  // load this wave's 8 z-lines (rows y = wv*8+l) into registers
  float rlo[8], ilo[8], rhi[8], ihi[8];
#pragma unroll
  for (int l = 0; l < 8; ++l) {
    const int row = ((wv << 3) | l) << 7;
    rlo[l] = r0[row + lane];  rhi[l] = r0[row + lane + 64];
    ilo[l] = r1[row + lane];  ihi[l] = r1[row + lane + 64];
  }
  __syncthreads();                       // twiddles ready
#pragma unroll
  for (int l = 0; l < 8; ++l) {
    sh_fwd(rlo[l], ilo[l], rhi[l], ihi[l], lane, twr, twi);
    const int y = (wv << 3) | l;
    s_re[y * 129 + lane] = rlo[l];  s_re[y * 129 + lane + 64] = rhi[l];
    s_im[y * 129 + lane] = ilo[l];  s_im[y * 129 + lane + 64] = ihi[l];
  }
  __syncthreads();
  // y-FFT: wave handles columns z = wv*8+l
#pragma unroll
  for (int l = 0; l < 8; ++l) {
    const int z = (wv << 3) | l;
    float arl = s_re[lane * 129 + z],        ail = s_im[lane * 129 + z];
    float arh = s_re[(lane + 64) * 129 + z], aih = s_im[(lane + 64) * 129 + z];
    sh_fwd(arl, ail, arh, aih, lane, twr, twi);
    s_re[lane * 129 + z] = arl;  s_re[(lane + 64) * 129 + z] = arh;
    s_im[lane * 129 + z] = ail;  s_im[(lane + 64) * 129 + z] = aih;
  }
  __syncthreads();
  float2* cb = cbuf + (size_t)p * VV + (size_t)x * 16384;
#pragma unroll
  for (int i = 0; i < 16; ++i) {
    const int e = tid + i * 1024, y = e >> 7, z = e & 127;
    cb[e] = make_float2(s_re[y * 129 + z], s_im[y * 129 + z]);
  }
}

// ---------------- fused y+z inverse FFT over one x-plane --------------------
// bulk load -> LDS -> regs(y-inv) -> LDS -> regs(z-inv) -> direct store.
__global__ __launch_bounds__(1024) void k_fft_zy_i(float2* __restrict__ cbuf) {
  __shared__ float twr[64], twi[64];
  __shared__ float s_re[128 * 129], s_im[128 * 129];
  const int tid = threadIdx.x, lane = tid & 63, wv = tid >> 6;
  if (tid < 64) {
    float s, c; sincosf((float)tid * K_W0, &s, &c);
    twr[tid] = c; twi[tid] = s;
  }
  const int p = blockIdx.x >> 7, x = blockIdx.x & 127;
  float2* cb = cbuf + (size_t)p * VV + (size_t)x * 16384;
#pragma unroll
  for (int i = 0; i < 16; ++i) {
    const int e = tid + i * 1024, y = e >> 7, z = e & 127;
    const float2 v = cb[e];
    s_re[y * 129 + z] = v.x;  s_im[y * 129 + z] = v.y;
  }
  __syncthreads();
  // y-inverse on columns z = wv*8+l
#pragma unroll
  for (int l = 0; l < 8; ++l) {
    const int z = (wv << 3) | l;
    float arl = s_re[lane * 129 + z],        ail = s_im[lane * 129 + z];
    float arh = s_re[(lane + 64) * 129 + z], aih = s_im[(lane + 64) * 129 + z];
    sh_inv(arl, ail, arh, aih, lane, twr, twi);
    s_re[lane * 129 + z] = arl;  s_re[(lane + 64) * 129 + z] = arh;
    s_im[lane * 129 + z] = ail;  s_im[(lane + 64) * 129 + z] = aih;
  }
  __syncthreads();
  // z-inverse on rows y = wv*8+l, store directly (coalesced float2 rows)
#pragma unroll
  for (int l = 0; l < 8; ++l) {
    const int y = (wv << 3) | l;
    float arl = s_re[y * 129 + lane],      ail = s_im[y * 129 + lane];
    float arh = s_re[y * 129 + lane + 64], aih = s_im[y * 129 + lane + 64];
    sh_inv(arl, ail, arh, aih, lane, twr, twi);
    cb[(y << 7) + lane]      = make_float2(arl, ail);
    cb[(y << 7) + lane + 64] = make_float2(arh, aih);
  }
}

// ---------------- fused fwd-x FFT + spectral scale + inv-x FFT --------------
// z-tile of 16 for fixed (vol, y). LDS [x][zz] stride 17 (coprime 32 ->
// conflict-free x-columns). FFTs in registers via shfl; scale in registers.
// tt[p] = 2-2cos(2*pi*bitrev7(p)/128): t at bit-reversed storage positions.
__global__ __launch_bounds__(512) void k_fft_x_fused(float2* __restrict__ cbuf) {
  __shared__ float twr[64], twi[64], tt[128];
  __shared__ float s_re[128 * 17], s_im[128 * 17];
  const int tid = threadIdx.x, lane = tid & 63, wv = tid >> 6;   // 8 waves
  if (tid < 64) {
    float s, c; sincosf((float)tid * K_W0, &s, &c);
    twr[tid] = c; twi[tid] = s;
  }
  if (tid < 128) {
    const int br = (int)(__brev((unsigned)tid) >> 25);   // 7-bit bit-reverse
    tt[tid] = 2.0f - 2.0f * cosf((float)br * K_W0);
  }
  const int bid = blockIdx.x;                 // 3 * 128 * 8
  const int p = bid >> 10, rem = bid & 1023;
  const int y = rem >> 3, z0 = (rem & 7) << 4;
  float2* base = cbuf + (size_t)p * VV + (size_t)(y * 128 + z0);
#pragma unroll
  for (int i = 0; i < 4; ++i) {
    const int e = tid + i * 512, xx = e >> 4, zz = e & 15;
    const float2 v = base[(size_t)xx * 16384 + zz];
    s_re[xx * 17 + zz] = v.x;  s_im[xx * 17 + zz] = v.y;
  }
  __syncthreads();
  const float tyv = tt[y];
#pragma unroll
  for (int l = 0; l < 2; ++l) {
    const int zz = wv + (l << 3);
    float arl = s_re[lane * 17 + zz],        ail = s_im[lane * 17 + zz];
    float arh = s_re[(lane + 64) * 17 + zz], aih = s_im[(lane + 64) * 17 + zz];
    sh_fwd(arl, ail, arh, aih, lane, twr, twi);
    const float tzv = tt[z0 + zz];
    const float slo = K_DTN3 / (K_GAMMA + K_ALPHA * (tt[lane] + tyv + tzv));
    const float shi = K_DTN3 / (K_GAMMA + K_ALPHA * (tt[lane + 64] + tyv + tzv));
    arl *= slo;  ail *= slo;  arh *= shi;  aih *= shi;
    sh_inv(arl, ail, arh, aih, lane, twr, twi);
    s_re[lane * 17 + zz] = arl;  s_re[(lane + 64) * 17 + zz] = arh;
    s_im[lane * 17 + zz] = ail;  s_im[(lane + 64) * 17 + zz] = aih;
  }
  __syncthreads();
#pragma unroll
  for (int i = 0; i < 4; ++i) {
    const int e = tid + i * 512, xx = e >> 4, zz = e & 15;
    base[(size_t)xx * 16384 + zz] = make_float2(s_re[xx * 17 + zz], s_im[xx * 17 + zz]);
  }
}

// ---------------- pullback: asm-batched gathers (48 loads in flight) --------
// The compiler schedules plain gathers for minimal VGPR (round 9: VGPR=32,
// ~4 loads in flight, latency-bound at 147us). asm volatile global_load
// forces all 48 issues before one s_waitcnt; sched_barrier(0) stops the
// reduction FMAs from hoisting past the wait (guide rule #18).
__device__ __forceinline__ void gload(float& dst, const float* p) {
  asm volatile("global_load_dword %0, %1, off" : "=v"(dst) : "v"(p));
}

__global__ __launch_bounds__(256) void k_pullback(const float* __restrict__ svc,
                                                  const float* __restrict__ phiA,
                                                  const float* __restrict__ mA,
                                                  float* __restrict__ phiB,
                                                  float* __restrict__ mB) {
  const int idx = blockIdx.x * 256 + threadIdx.x;   // over 2*VV
  const int b   = idx >> 21;
  const int vox = idx & (VV - 1);
  const int z = vox & 127, y = (vox >> 7) & 127, x = vox >> 14;
  // sv channel r=b*3+c lives at complex vol r>>1, component r&1
  const int r0 = b * 3;
  const float d0 = svc[(size_t)((r0)     >> 1) * 2 * VV + ((size_t)vox << 1) + ((r0)     & 1)];
  const float d1 = svc[(size_t)((r0 + 1) >> 1) * 2 * VV + ((size_t)vox << 1) + ((r0 + 1) & 1)];
  const float d2 = svc[(size_t)((r0 + 2) >> 1) * 2 * VV + ((size_t)vox << 1) + ((r0 + 2) & 1)];
  const float cx = (float)x + d0, cy = (float)y + d1, cz = (float)z + d2;
  const float flx = floorf(cx), fly = floorf(cy), flz = floorf(cz);
  const float wx = cx - flx, wy = cy - fly, wz = cz - flz;
  const int x0 = ((int)flx) & 127, y0 = ((int)fly) & 127, z0 = ((int)flz) & 127;
  const int x1 = (x0 + 1) & 127,  y1 = (y0 + 1) & 127,  z1 = (z0 + 1) & 127;
  int o[8];
  o[0] = (x0 * 128 + y0) * 128 + z0;  o[1] = (x0 * 128 + y0) * 128 + z1;
  o[2] = (x0 * 128 + y1) * 128 + z0;  o[3] = (x0 * 128 + y1) * 128 + z1;
  o[4] = (x1 * 128 + y0) * 128 + z0;  o[5] = (x1 * 128 + y0) * 128 + z1;
  o[6] = (x1 * 128 + y1) * 128 + z0;  o[7] = (x1 * 128 + y1) * 128 + z1;
  const size_t sb = (size_t)b * 3 * VV;
  const float* bs[6] = { phiA + sb, phiA + sb + VV, phiA + sb + 2 * (size_t)VV,
                         mA   + sb, mA   + sb + VV, mA   + sb + 2 * (size_t)VV };
  // -------- issue ALL 48 gathers (program-ordered asm, no implicit waits) ---
  float g[6][8];
#pragma unroll
  for (int c = 0; c < 6; ++c)
#pragma unroll
    for (int k = 0; k < 8; ++k)
      gload(g[c][k], bs[c] + o[k]);
  // weights (VALU; overlaps the in-flight loads)
  const float ux = 1.f - wx, uy = 1.f - wy, uz = 1.f - wz;
  float w[8];
  w[0] = ux * uy * uz;  w[1] = ux * uy * wz;
  w[2] = ux * wy * uz;  w[3] = ux * wy * wz;
  w[4] = wx * uy * uz;  w[5] = wx * uy * wz;
  w[6] = wx * wy * uz;  w[7] = wx * wy * wz;
  const float dd[3] = {d0, d1, d2};
  asm volatile("s_waitcnt vmcnt(0)" ::: "memory");
  __builtin_amdgcn_sched_barrier(0);
  // -------- reduce + store --------
#pragma unroll
  for (int c = 0; c < 3; ++c) {
    float sp = 0.f, sm = 0.f;
#pragma unroll
    for (int k = 0; k < 8; ++k) { sp += w[k] * g[c][k];  sm += w[k] * g[3 + c][k]; }
    phiB[sb + (size_t)c * VV + vox] = sp + dd[c];
    mB[sb + (size_t)c * VV + vox]   = sm;
  }
}

// ---------------- host ------------------------------------------------------
// ws layout (floats): [phi1: 6*VV][mA: 6*VV][mB: 6*VV][cbuf: 3*VV complex]
// total 4 * 6*VV * 4B = 192 MiB.
extern "C" void kernel_launch(void* const* d_in, const int* in_sizes, int n_in,
                              void* d_out, int out_size, void* d_ws, size_t ws_size,
                              hipStream_t stream) {
  (void)in_sizes; (void)n_in; (void)out_size; (void)ws_size;
  const float* v = (const float*)d_in[0];
  float* phi0 = (float*)d_out;                       // phi buffer A (result here)
  float* ws   = (float*)d_ws;
  const size_t FV = (size_t)6 * VV;                  // floats per full field
  float* phi1 = ws;                                  // phi buffer B
  float* mA   = ws + FV;
  float* mB   = ws + 2 * FV;
  float2* cbuf = (float2*)(ws + 3 * FV);             // 3 complex vols (= sv packed)

  hipMemsetAsync(phi0, 0, FV * sizeof(float), stream);
  k_stencil_L<<<dim3((unsigned)(FV / 256)), dim3(256), 0, stream>>>(v, mA);

  float* phiA = phi0; float* phiB = phi1;
  float* ma = mA;     float* mb = mB;
  for (int s = 0; s < 8; ++s) {
    k_fft_zy_f<<<dim3(384), dim3(1024), 0, stream>>>(ma, cbuf);
    k_fft_x_fused<<<dim3(3072), dim3(512), 0, stream>>>(cbuf);
    k_fft_zy_i<<<dim3(384), dim3(1024), 0, stream>>>(cbuf);
    k_pullback<<<dim3(16384), dim3(256), 0, stream>>>((const float*)cbuf,
                                                      phiA, ma, phiB, mb);
    float* t = phiA; phiA = phiB; phiB = t;
    t = ma; ma = mb; mb = t;
  }
  // 8 swaps (even): final phi ends in d_out
}

// Round 12
// 2135.855 us; speedup vs baseline: 1.2638x; 1.1314x over previous
//
#include <hip/hip_runtime.h>
#include <math.h>

#define VV (128*128*128)         // 2,097,152 voxels per volume

#define K_GAMMA 1e-3f
#define K_ALPHA 1e-2f
#define K_DTN3  5.9604644775390625e-08f   // (1/8) / 128^3  == 2^-24
#define K_W0    0.04908738521234052f      // 2*pi/128

// ============ shuffle-register FFT, N=128, one line per 64-lane wave ========
// Mapping: lane l holds positions l (lo) and l+64 (hi) — fixed through all
// stages, so storage order matches the (verified) LDS in-place DIF/DIT:
// fwd DIF natural->bit-reversed (W^-), inv DIT bit-reversed->natural (W^+).
// Stage h=64 is in-lane; stages h<=32 exchange via __shfl_xor(h).
__device__ __forceinline__ void sh_fwd(float& rlo, float& ilo, float& rhi, float& ihi,
                                       const int lane,
                                       const float* __restrict__ twr,
                                       const float* __restrict__ twi) {
  {   // lh=6, h=64: pair (l, l+64) in-lane, tw idx = l
    const float wr = twr[lane], ws = twi[lane];
    const float dr = rlo - rhi, di = ilo - ihi;
    rlo += rhi;  ilo += ihi;
    rhi = dr * wr + di * ws;    // (dr + i di)*(wr - i ws)
    ihi = di * wr - dr * ws;
  }
#pragma unroll
  for (int lh = 5; lh >= 0; --lh) {
    const int h  = 1 << lh;
    const int up = lane & h;
    const int ti = (lane & (h - 1)) << (6 - lh);
    const float wr = twr[ti], ws = twi[ti];
    float pr = __shfl_xor(rlo, h), pi = __shfl_xor(ilo, h);
    float dr = up ? (pr - rlo) : (rlo + pr);
    float di = up ? (pi - ilo) : (ilo + pi);
    rlo = up ? (dr * wr + di * ws) : dr;
    ilo = up ? (di * wr - dr * ws) : di;
    pr = __shfl_xor(rhi, h);  pi = __shfl_xor(ihi, h);
    dr = up ? (pr - rhi) : (rhi + pr);
    di = up ? (pi - ihi) : (ihi + pi);
    rhi = up ? (dr * wr + di * ws) : dr;
    ihi = up ? (di * wr - dr * ws) : di;
  }
}

__device__ __forceinline__ void sh_inv(float& rlo, float& ilo, float& rhi, float& ihi,
                                       const int lane,
                                       const float* __restrict__ twr,
                                       const float* __restrict__ twi) {
#pragma unroll
  for (int lh = 0; lh <= 5; ++lh) {
    const int h  = 1 << lh;
    const int up = lane & h;
    const int ti = (lane & (h - 1)) << (6 - lh);
    const float wr = twr[ti], ws = twi[ti];
    float pr = __shfl_xor(rlo, h), pi = __shfl_xor(ilo, h);
    float ar = up ? pr : rlo,  ai = up ? pi : ilo;
    float br = up ? rlo : pr,  bi = up ? ilo : pi;
    float cr = br * wr - bi * ws, ci = br * ws + bi * wr;   // b * (wr + i ws)
    rlo = up ? (ar - cr) : (ar + cr);
    ilo = up ? (ai - ci) : (ai + ci);
    pr = __shfl_xor(rhi, h);  pi = __shfl_xor(ihi, h);
    ar = up ? pr : rhi;  ai = up ? pi : ihi;
    br = up ? rhi : pr;  bi = up ? ihi : pi;
    cr = br * wr - bi * ws;  ci = br * ws + bi * wr;
    rhi = up ? (ar - cr) : (ar + cr);
    ihi = up ? (ai - ci) : (ai + ci);
  }
  {   // lh=6, h=64 in-lane, tw idx = l
    const float wr = twr[lane], ws = twi[lane];
    const float cr = rhi * wr - ihi * ws, ci = rhi * ws + ihi * wr;
    rhi = rlo - cr;  ihi = ilo - ci;
    rlo += cr;       ilo += ci;
  }
}

// ---------------- K1: m = L v = gamma*v + alpha*(6v - sum of 6 nbrs) --------
__global__ __launch_bounds__(256) void k_stencil_L(const float* __restrict__ v,
                                                   float* __restrict__ m) {
  const int idx = blockIdx.x * 256 + threadIdx.x;   // over 6*VV
  const int vox = idx & (VV - 1);
  const int r   = idx >> 21;
  const int z = vox & 127, y = (vox >> 7) & 127, x = vox >> 14;
  const float* base = v + (size_t)r * VV;
  const float c = base[vox];
  const int xm = (x - 1) & 127, xp = (x + 1) & 127;
  const int ym = (y - 1) & 127, yp = (y + 1) & 127;
  const int zm = (z - 1) & 127, zp = (z + 1) & 127;
  const float nsum = base[(xm << 14) | (y << 7) | z] + base[(xp << 14) | (y << 7) | z]
                   + base[(x << 14) | (ym << 7) | z] + base[(x << 14) | (yp << 7) | z]
                   + base[(x << 14) | (y << 7) | zm] + base[(x << 14) | (y << 7) | zp];
  m[idx] = K_GAMMA * c + K_ALPHA * (6.0f * c - nsum);
}

// ---------------- fused z+y forward FFT over one x-plane --------------------
__global__ __launch_bounds__(1024) void k_fft_zy_f(const float* __restrict__ m,
                                                   float2* __restrict__ cbuf) {
  __shared__ float twr[64], twi[64];
  __shared__ float s_re[128 * 129], s_im[128 * 129];
  const int tid = threadIdx.x, lane = tid & 63, wv = tid >> 6;   // 16 waves
  if (tid < 64) {
    float s, c; sincosf((float)tid * K_W0, &s, &c);
    twr[tid] = c; twi[tid] = s;
  }
  const int p = blockIdx.x >> 7, x = blockIdx.x & 127;
  const float* r0 = m + (size_t)(2 * p) * VV + (size_t)x * 16384;
  const float* r1 = r0 + VV;
  float rlo[8], ilo[8], rhi[8], ihi[8];
#pragma unroll
  for (int l = 0; l < 8; ++l) {
    const int row = ((wv << 3) | l) << 7;
    rlo[l] = r0[row + lane];  rhi[l] = r0[row + lane + 64];
    ilo[l] = r1[row + lane];  ihi[l] = r1[row + lane + 64];
  }
  __syncthreads();                       // twiddles ready
#pragma unroll
  for (int l = 0; l < 8; ++l) {
    sh_fwd(rlo[l], ilo[l], rhi[l], ihi[l], lane, twr, twi);
    const int y = (wv << 3) | l;
    s_re[y * 129 + lane] = rlo[l];  s_re[y * 129 + lane + 64] = rhi[l];
    s_im[y * 129 + lane] = ilo[l];  s_im[y * 129 + lane + 64] = ihi[l];
  }
  __syncthreads();
#pragma unroll
  for (int l = 0; l < 8; ++l) {
    const int z = (wv << 3) | l;
    float arl = s_re[lane * 129 + z],        ail = s_im[lane * 129 + z];
    float arh = s_re[(lane + 64) * 129 + z], aih = s_im[(lane + 64) * 129 + z];
    sh_fwd(arl, ail, arh, aih, lane, twr, twi);
    s_re[lane * 129 + z] = arl;  s_re[(lane + 64) * 129 + z] = arh;
    s_im[lane * 129 + z] = ail;  s_im[(lane + 64) * 129 + z] = aih;
  }
  __syncthreads();
  float2* cb = cbuf + (size_t)p * VV + (size_t)x * 16384;
#pragma unroll
  for (int i = 0; i < 16; ++i) {
    const int e = tid + i * 1024, y = e >> 7, z = e & 127;
    cb[e] = make_float2(s_re[y * 129 + z], s_im[y * 129 + z]);
  }
}

// ---------------- fused y+z inverse FFT over one x-plane --------------------
__global__ __launch_bounds__(1024) void k_fft_zy_i(float2* __restrict__ cbuf) {
  __shared__ float twr[64], twi[64];
  __shared__ float s_re[128 * 129], s_im[128 * 129];
  const int tid = threadIdx.x, lane = tid & 63, wv = tid >> 6;
  if (tid < 64) {
    float s, c; sincosf((float)tid * K_W0, &s, &c);
    twr[tid] = c; twi[tid] = s;
  }
  const int p = blockIdx.x >> 7, x = blockIdx.x & 127;
  float2* cb = cbuf + (size_t)p * VV + (size_t)x * 16384;
#pragma unroll
  for (int i = 0; i < 16; ++i) {
    const int e = tid + i * 1024, y = e >> 7, z = e & 127;
    const float2 v = cb[e];
    s_re[y * 129 + z] = v.x;  s_im[y * 129 + z] = v.y;
  }
  __syncthreads();
#pragma unroll
  for (int l = 0; l < 8; ++l) {
    const int z = (wv << 3) | l;
    float arl = s_re[lane * 129 + z],        ail = s_im[lane * 129 + z];
    float arh = s_re[(lane + 64) * 129 + z], aih = s_im[(lane + 64) * 129 + z];
    sh_inv(arl, ail, arh, aih, lane, twr, twi);
    s_re[lane * 129 + z] = arl;  s_re[(lane + 64) * 129 + z] = arh;
    s_im[lane * 129 + z] = ail;  s_im[(lane + 64) * 129 + z] = aih;
  }
  __syncthreads();
#pragma unroll
  for (int l = 0; l < 8; ++l) {
    const int y = (wv << 3) | l;
    float arl = s_re[y * 129 + lane],      ail = s_im[y * 129 + lane];
    float arh = s_re[y * 129 + lane + 64], aih = s_im[y * 129 + lane + 64];
    sh_inv(arl, ail, arh, aih, lane, twr, twi);
    cb[(y << 7) + lane]      = make_float2(arl, ail);
    cb[(y << 7) + lane + 64] = make_float2(arh, aih);
  }
}

// ---------------- fused fwd-x FFT + spectral scale + inv-x FFT --------------
__global__ __launch_bounds__(512) void k_fft_x_fused(float2* __restrict__ cbuf) {
  __shared__ float twr[64], twi[64], tt[128];
  __shared__ float s_re[128 * 17], s_im[128 * 17];
  const int tid = threadIdx.x, lane = tid & 63, wv = tid >> 6;   // 8 waves
  if (tid < 64) {
    float s, c; sincosf((float)tid * K_W0, &s, &c);
    twr[tid] = c; twi[tid] = s;
  }
  if (tid < 128) {
    const int br = (int)(__brev((unsigned)tid) >> 25);   // 7-bit bit-reverse
    tt[tid] = 2.0f - 2.0f * cosf((float)br * K_W0);
  }
  const int bid = blockIdx.x;                 // 3 * 128 * 8
  const int p = bid >> 10, rem = bid & 1023;
  const int y = rem >> 3, z0 = (rem & 7) << 4;
  float2* base = cbuf + (size_t)p * VV + (size_t)(y * 128 + z0);
#pragma unroll
  for (int i = 0; i < 4; ++i) {
    const int e = tid + i * 512, xx = e >> 4, zz = e & 15;
    const float2 v = base[(size_t)xx * 16384 + zz];
    s_re[xx * 17 + zz] = v.x;  s_im[xx * 17 + zz] = v.y;
  }
  __syncthreads();
  const float tyv = tt[y];
#pragma unroll
  for (int l = 0; l < 2; ++l) {
    const int zz = wv + (l << 3);
    float arl = s_re[lane * 17 + zz],        ail = s_im[lane * 17 + zz];
    float arh = s_re[(lane + 64) * 17 + zz], aih = s_im[(lane + 64) * 17 + zz];
    sh_fwd(arl, ail, arh, aih, lane, twr, twi);
    const float tzv = tt[z0 + zz];
    const float slo = K_DTN3 / (K_GAMMA + K_ALPHA * (tt[lane] + tyv + tzv));
    const float shi = K_DTN3 / (K_GAMMA + K_ALPHA * (tt[lane + 64] + tyv + tzv));
    arl *= slo;  ail *= slo;  arh *= shi;  aih *= shi;
    sh_inv(arl, ail, arh, aih, lane, twr, twi);
    s_re[lane * 17 + zz] = arl;  s_re[(lane + 64) * 17 + zz] = arh;
    s_im[lane * 17 + zz] = ail;  s_im[(lane + 64) * 17 + zz] = aih;
  }
  __syncthreads();
#pragma unroll
  for (int i = 0; i < 4; ++i) {
    const int e = tid + i * 512, xx = e >> 4, zz = e & 15;
    base[(size_t)xx * 16384 + zz] = make_float2(s_re[xx * 17 + zz], s_im[xx * 17 + zz]);
  }
}

// ---------------- pullback: LDS-tiled gather --------------------------------
// 4x4x32 output tile + 1-voxel halo (6x6x34, z padded to 36) of all 6
// transport channels staged to LDS as float2 (phi_c, m_c share corners ->
// ds_read_b64). Global reads become streaming/coalesced; gathers hit LDS.
// |disp| < 1 for this problem (sv ~ dt*K(m) ~ 0.06 voxel rms); a per-voxel
// global fallback keeps correctness for arbitrary inputs.
__global__ __launch_bounds__(256) void k_pullback_t(const float* __restrict__ svc,
                                                    const float* __restrict__ phiA,
                                                    const float* __restrict__ mA,
                                                    float* __restrict__ phiB,
                                                    float* __restrict__ mB) {
  __shared__ float2 TP[3][6][6][36];   // [ch_pair][rx][ry][rz] = (phi_c, m_c)
  __shared__ float  S[3][512];         // sv channels for the output tile
  const int tid = threadIdx.x;
  const int bid = blockIdx.x;          // 8192 = 2 batches * 32 * 32 * 4 tiles
  const int b  = bid >> 12;
  const int rr = bid & 4095;
  const int X = ((rr >> 7) & 31) << 2;
  const int Y = ((rr >> 2) & 31) << 2;
  const int Z = (rr & 3) << 5;
  const size_t sb = (size_t)b * 3 * VV;
  // ---- stage transport halo tile (rz 34..35 are padding, never gathered) ---
  for (int j = tid; j < 3 * 1296; j += 256) {
    const int cp  = j / 1296;
    const int rm  = j - cp * 1296;
    const int rx  = rm / 216;
    const int rm2 = rm - rx * 216;
    const int ry  = rm2 / 36;
    const int rz  = rm2 - ry * 36;
    const int g = (((X - 1 + rx) & 127) << 14) | (((Y - 1 + ry) & 127) << 7)
                | ((Z - 1 + rz) & 127);
    TP[cp][rx][ry][rz] = make_float2(phiA[sb + (size_t)cp * VV + g],
                                     mA[sb + (size_t)cp * VV + g]);
  }
  // ---- stage sv for the output tile ----
  for (int j = tid; j < 1536; j += 256) {
    const int c = j >> 9, v = j & 511;
    const int slz = v & 31, sly = (v >> 5) & 3, slx = v >> 7;
    const int g = ((X + slx) << 14) | ((Y + sly) << 7) | (Z + slz);
    const int rch = b * 3 + c;
    S[c][v] = svc[(size_t)(rch >> 1) * 2 * VV + ((size_t)g << 1) + (rch & 1)];
  }
  __syncthreads();
  const int lz = tid & 31, ly = (tid >> 5) & 3, lx0 = tid >> 7;
#pragma unroll
  for (int q = 0; q < 2; ++q) {
    const int lx = lx0 + (q << 1);
    const int v  = (lx << 7) | (ly << 5) | lz;
    const float d0 = S[0][v], d1 = S[1][v], d2 = S[2][v];
    const int gx = X + lx, gy = Y + ly, gz = Z + lz;
    const float cx = (float)gx + d0, cy = (float)gy + d1, cz = (float)gz + d2;
    const float flx = floorf(cx), fly = floorf(cy), flz = floorf(cz);
    const float wx = cx - flx, wy = cy - fly, wz = cz - flz;
    const float ux = 1.f - wx, uy = 1.f - wy, uz = 1.f - wz;
    const float w000 = ux * uy * uz, w001 = ux * uy * wz;
    const float w010 = ux * wy * uz, w011 = ux * wy * wz;
    const float w100 = wx * uy * uz, w101 = wx * uy * wz;
    const float w110 = wx * wy * uz, w111 = wx * wy * wz;
    const int x0l = (int)flx - (X - 1);
    const int y0l = (int)fly - (Y - 1);
    const int z0l = (int)flz - (Z - 1);
    const int g = (gx << 14) | (gy << 7) | gz;
    const float dd[3] = {d0, d1, d2};
    if ((unsigned)x0l <= 4u && (unsigned)y0l <= 4u && (unsigned)z0l <= 32u) {
#pragma unroll
      for (int cp = 0; cp < 3; ++cp) {
        const float2 c000 = TP[cp][x0l][y0l][z0l];
        const float2 c001 = TP[cp][x0l][y0l][z0l + 1];
        const float2 c010 = TP[cp][x0l][y0l + 1][z0l];
        const float2 c011 = TP[cp][x0l][y0l + 1][z0l + 1];
        const float2 c100 = TP[cp][x0l + 1][y0l][z0l];
        const float2 c101 = TP[cp][x0l + 1][y0l][z0l + 1];
        const float2 c110 = TP[cp][x0l + 1][y0l + 1][z0l];
        const float2 c111 = TP[cp][x0l + 1][y0l + 1][z0l + 1];
        const float sp = w000 * c000.x + w001 * c001.x + w010 * c010.x + w011 * c011.x
                       + w100 * c100.x + w101 * c101.x + w110 * c110.x + w111 * c111.x;
        const float sm = w000 * c000.y + w001 * c001.y + w010 * c010.y + w011 * c011.y
                       + w100 * c100.y + w101 * c101.y + w110 * c110.y + w111 * c111.y;
        phiB[sb + (size_t)cp * VV + g] = sp + dd[cp];
        mB[sb + (size_t)cp * VV + g]   = sm;
      }
    } else {
      // global fallback (arbitrary displacement; not taken for this input)
      const int xg0 = ((int)flx) & 127, yg0 = ((int)fly) & 127, zg0 = ((int)flz) & 127;
      const int xg1 = (xg0 + 1) & 127, yg1 = (yg0 + 1) & 127, zg1 = (zg0 + 1) & 127;
      int o[8];
      o[0] = (xg0 * 128 + yg0) * 128 + zg0;  o[1] = (xg0 * 128 + yg0) * 128 + zg1;
      o[2] = (xg0 * 128 + yg1) * 128 + zg0;  o[3] = (xg0 * 128 + yg1) * 128 + zg1;
      o[4] = (xg1 * 128 + yg0) * 128 + zg0;  o[5] = (xg1 * 128 + yg0) * 128 + zg1;
      o[6] = (xg1 * 128 + yg1) * 128 + zg0;  o[7] = (xg1 * 128 + yg1) * 128 + zg1;
      const float w[8] = {w000, w001, w010, w011, w100, w101, w110, w111};
#pragma unroll
      for (int cp = 0; cp < 3; ++cp) {
        const float* P = phiA + sb + (size_t)cp * VV;
        const float* M = mA + sb + (size_t)cp * VV;
        float sp = 0.f, sm = 0.f;
#pragma unroll
        for (int k = 0; k < 8; ++k) { sp += w[k] * P[o[k]]; sm += w[k] * M[o[k]]; }
        phiB[sb + (size_t)cp * VV + g] = sp + dd[cp];
        mB[sb + (size_t)cp * VV + g]   = sm;
      }
    }
  }
}

// ---------------- host ------------------------------------------------------
// ws layout (floats): [phi1: 6*VV][mA: 6*VV][mB: 6*VV][cbuf: 3*VV complex]
// total 4 * 6*VV * 4B = 192 MiB.
extern "C" void kernel_launch(void* const* d_in, const int* in_sizes, int n_in,
                              void* d_out, int out_size, void* d_ws, size_t ws_size,
                              hipStream_t stream) {
  (void)in_sizes; (void)n_in; (void)out_size; (void)ws_size;
  const float* v = (const float*)d_in[0];
  float* phi0 = (float*)d_out;                       // phi buffer A (result here)
  float* ws   = (float*)d_ws;
  const size_t FV = (size_t)6 * VV;                  // floats per full field
  float* phi1 = ws;                                  // phi buffer B
  float* mA   = ws + FV;
  float* mB   = ws + 2 * FV;
  float2* cbuf = (float2*)(ws + 3 * FV);             // 3 complex vols (= sv packed)

  hipMemsetAsync(phi0, 0, FV * sizeof(float), stream);
  k_stencil_L<<<dim3((unsigned)(FV / 256)), dim3(256), 0, stream>>>(v, mA);

  float* phiA = phi0; float* phiB = phi1;
  float* ma = mA;     float* mb = mB;
  for (int s = 0; s < 8; ++s) {
    k_fft_zy_f<<<dim3(384), dim3(1024), 0, stream>>>(ma, cbuf);
    k_fft_x_fused<<<dim3(3072), dim3(512), 0, stream>>>(cbuf);
    k_fft_zy_i<<<dim3(384), dim3(1024), 0, stream>>>(cbuf);
    k_pullback_t<<<dim3(8192), dim3(256), 0, stream>>>((const float*)cbuf,
                                                       phiA, ma, phiB, mb);
    float* t = phiA; phiA = phiB; phiB = t;
    t = ma; ma = mb; mb = t;
  }
  // 8 swaps (even): final phi ends in d_out
}